// Round 7
// baseline (404.390 us; speedup 1.0000x reference)
//
#include <hip/hip_runtime.h>

// ---------- types ----------
typedef __attribute__((ext_vector_type(8)))  short  s8v;    // 8 bf16 (as shorts) = 4 VGPR
typedef __attribute__((ext_vector_type(8)))  unsigned short us8;
typedef __attribute__((ext_vector_type(4)))  float  f4v;
typedef __attribute__((ext_vector_type(16))) float  f16v;   // 32x32 MFMA accumulator

// float -> bf16 round-to-nearest-even (inputs are finite)
__device__ __forceinline__ unsigned short f2bf(float f) {
  unsigned int u = __builtin_bit_cast(unsigned int, f);
  u += 0x7fffu + ((u >> 16) & 1u);
  return (unsigned short)(u >> 16);
}

// async global->LDS, 16B per lane, offset arg ALWAYS 0 (only verified mode);
// any byte offset must be folded into the global pointer expression.
__device__ __forceinline__ void gll16(const void* g, void* l) {
  __builtin_amdgcn_global_load_lds(
      (const __attribute__((address_space(1))) unsigned int*)g,
      (__attribute__((address_space(3))) unsigned int*)l, 16, 0, 0);
}

// ---------- kernel 1: x fp32 -> bf16 ----------
__global__ __launch_bounds__(256) void cast_bf16(const float* __restrict__ in,
                                                 unsigned short* __restrict__ out) {
  const size_t i = (size_t)blockIdx.x * 256 + threadIdx.x;
  const f4v* p = (const f4v*)in;
  f4v a = p[2 * i];
  f4v b = p[2 * i + 1];
  us8 r;
  r[0] = f2bf(a[0]); r[1] = f2bf(a[1]); r[2] = f2bf(a[2]); r[3] = f2bf(a[3]);
  r[4] = f2bf(b[0]); r[5] = f2bf(b[1]); r[6] = f2bf(b[2]); r[7] = f2bf(b[3]);
  *(us8*)&out[i * 8] = r;
}

// ---------- kernel 2: T[o1,i1,o2,i2,r2] = sum_r1 core0*core1 ----------
__global__ __launch_bounds__(256) void contract1(const float* __restrict__ c0,
                                                 const float* __restrict__ c1,
                                                 float* __restrict__ T) {
  const int idx = blockIdx.x * 256 + threadIdx.x;
  const int r2  = idx & 63;
  const int oi2 = (idx >> 6) & 255;
  const int oi1 = idx >> 14;
  const float* c0p = c0 + oi1 * 64;
  const float* c1p = c1 + oi2 * 64 + r2;
  float s = 0.f;
#pragma unroll 8
  for (int r1 = 0; r1 < 64; ++r1)
    s = fmaf(c0p[r1], c1p[r1 * 16384], s);
  T[idx] = s;
}

// ---------- kernel 3: W build, LDS-staged ----------
__global__ __launch_bounds__(1024) void buildW2(const float* __restrict__ T,
                                                const float* __restrict__ c2,
                                                unsigned short* __restrict__ W) {
  __shared__ float c2s[16384];      // 64 KB: [r2][o3][i3]
  __shared__ float Tl[16640];       // 65 KB: [ii][r2], stride 65

  const int tid = threadIdx.x;
  const int o1  = blockIdx.x >> 4;
  const int o2  = blockIdx.x & 15;

#pragma unroll
  for (int j = 0; j < 4; ++j)
    ((f4v*)c2s)[j * 1024 + tid] = ((const f4v*)c2)[j * 1024 + tid];

#pragma unroll
  for (int rr = 0; rr < 4; ++rr) {
    const int i1 = rr * 4 + (tid >> 8);
    const float* src = T + (size_t)(o1 * 16 + i1) * 16384 + o2 * 1024;
    const int c = tid & 255;
    f4v v = ((const f4v*)src)[c];
    float* dst = &Tl[(i1 * 16 + (c >> 4)) * 65 + (c & 15) * 4];
    dst[0] = v[0]; dst[1] = v[1]; dst[2] = v[2]; dst[3] = v[3];
  }
  __syncthreads();

  const int ii = tid & 255;
  const int i1 = ii >> 4, i2 = ii & 15;
#pragma unroll
  for (int k = 0; k < 4; ++k) {
    const int o3 = k * 4 + (tid >> 8);
    float acc[16];
#pragma unroll
    for (int j = 0; j < 16; ++j) acc[j] = 0.f;
    for (int r2 = 0; r2 < 64; ++r2) {
      const float t = Tl[ii * 65 + r2];
      const f4v* cp = (const f4v*)&c2s[r2 * 256 + o3 * 16];
      f4v c0q = cp[0], c1q = cp[1], c2q = cp[2], c3q = cp[3];
#pragma unroll
      for (int j = 0; j < 4; ++j) acc[j]      = fmaf(t, c0q[j], acc[j]);
#pragma unroll
      for (int j = 0; j < 4; ++j) acc[4 + j]  = fmaf(t, c1q[j], acc[4 + j]);
#pragma unroll
      for (int j = 0; j < 4; ++j) acc[8 + j]  = fmaf(t, c2q[j], acc[8 + j]);
#pragma unroll
      for (int j = 0; j < 4; ++j) acc[12 + j] = fmaf(t, c3q[j], acc[12 + j]);
    }
    us8 w0, w1;
#pragma unroll
    for (int j = 0; j < 8; ++j) { w0[j] = f2bf(acc[j]); w1[j] = f2bf(acc[8 + j]); }
    unsigned short* dst =
        &W[(size_t)(o1 * 256 + o2 * 16 + o3) * 4096 + i1 * 256 + i2 * 16];
    *(us8*)dst = w0;
    *((us8*)(dst + 8)) = w1;
  }
}

// ---------- kernel 4: 256x256-tile GEMM, 32x32x16 MFMA, 4-phase pipelined ----------
// A[M][K], B[N][K] bf16, C[M][N] fp32. M=8192, N=4096, K=4096.
// LDS (ushort idx): A: buf*16384 + kh*8192 + row*32 + slot*8 ; B: +32768.
// Swizzle: 16B-slot ^= (row>>1)&3 on read; inverse on global source (rule #21).
// Phase q (K=16 step): read frags for q+1 (reg dbuf), stage one half-tile,
// barrier, 8 MFMA (4 mf x 2 nf), [VMW(2) at q0/q2], barrier.
// 32x32x16 operand layout: A/B lane l -> row|col = l&31, k = (l>>5)*8+i.
// Within-row 16B slot for K-step Q: 2*(Q&1) + g  (kh = Q>>1 selects the half-tile).
// C/D (m74/m101): col = lane&31, row = (r&3) + 8*(r>>2) + 4*(lane>>5).

#define SBAR() do { asm volatile("" ::: "memory"); __builtin_amdgcn_s_barrier(); asm volatile("" ::: "memory"); } while (0)
#define VMW(N) asm volatile("s_waitcnt vmcnt(" #N ")" ::: "memory")

__device__ __forceinline__ void mm8(f16v (&acc)[4][2], const s8v (&aF)[4], const s8v (&bF)[2]) {
  __builtin_amdgcn_s_setprio(1);
#pragma unroll
  for (int mf = 0; mf < 4; ++mf) {
    acc[mf][0] = __builtin_amdgcn_mfma_f32_32x32x16_bf16(aF[mf], bF[0], acc[mf][0], 0, 0, 0);
    acc[mf][1] = __builtin_amdgcn_mfma_f32_32x32x16_bf16(aF[mf], bF[1], acc[mf][1], 0, 0, 0);
  }
  __builtin_amdgcn_s_setprio(0);
}

__global__ __launch_bounds__(512, 2) void gemm32(const unsigned short* __restrict__ A,
                                                 const unsigned short* __restrict__ B,
                                                 float* __restrict__ C) {
  constexpr int M = 8192, N = 4096, K = 4096;
  constexpr int NT = K / 64;      // 64 K-tiles
  constexpr int NXT = N / 256;    // 16 tiles in N

  __shared__ unsigned short lds[65536];   // 128 KiB

  const int tid  = threadIdx.x;
  const int lane = tid & 63;
  const int wid  = tid >> 6;      // 0..7
  const int wm   = wid >> 2;      // 0..1
  const int wn   = wid & 3;       // 0..3

  // XCD-aware bijective swizzle (gridDim.x = 512, divisible by 8)
  const int cpx = (int)gridDim.x >> 3;
  const int wg  = ((int)blockIdx.x & 7) * cpx + ((int)blockIdx.x >> 3);
  const long bm = (long)(wg / NXT) * 256;
  const long bn = (long)(wg % NXT) * 256;

  // ---- staging addressing (incremented pointers; kh folded into pointer, offset arg 0) ----
  const int r0  = tid >> 2;
  const int sx0 = (tid & 3) ^ ((r0 >> 1) & 3);    // inverse-swizzled global 16B slot
  const unsigned short* gA  = A + (bm + r0) * (size_t)K + sx0 * 8;
  const unsigned short* gA2 = gA + 128 * (size_t)K;
  const unsigned short* gB  = B + (bn + r0) * (size_t)K + sx0 * 8;
  const unsigned short* gB2 = gB + 128 * (size_t)K;
  const int ldst = tid * 8;                        // linear LDS dest (ushorts)

  // STAGE one half-tile: isB in {0,1}, KH literal in {0,1}, dstU = buf base (ushorts)
#define STAGE(isB, KH, dstU) do {                                                \
    const unsigned short* gl_ = (isB ? gB : gA) + (KH) * 32;                     \
    const unsigned short* gh_ = (isB ? gB2 : gA2) + (KH) * 32;                   \
    unsigned short* l_ = &lds[(isB ? 32768 : 0) + (dstU) + (KH) * 8192 + ldst];  \
    gll16(gl_, l_);                                                              \
    gll16(gh_, l_ + 4096);                                                       \
  } while (0)

  // ---- fragment read addressing ----
  const int l31  = lane & 31;
  const int g    = lane >> 5;                      // 0..1 : k-group
  const int mswz = (lane >> 1) & 3;                // slot-XOR mask ((row>>1)&3)
  const int arow = (wm * 128 + l31) * 32;          // ushort offset of A row
  const int brow = (wn * 64 + l31) * 32;

  // read frags for K-step Q (0..3) from buffer at bufU (0 or 16384 ushorts)
#define RD32(aD, bD, Q, bufU) do {                                               \
    const int sx_ = ((2 * ((Q) & 1) + g) ^ mswz) << 3;                           \
    const unsigned short* pa_ = &lds[(bufU) + ((Q) >> 1) * 8192 + arow + sx_];   \
    aD[0] = *(const s8v*)(pa_);        aD[1] = *(const s8v*)(pa_ + 1024);        \
    aD[2] = *(const s8v*)(pa_ + 2048); aD[3] = *(const s8v*)(pa_ + 3072);        \
    const unsigned short* pb_ = &lds[32768 + (bufU) + ((Q) >> 1) * 8192 + brow + sx_]; \
    bD[0] = *(const s8v*)(pb_);        bD[1] = *(const s8v*)(pb_ + 1024);        \
  } while (0)

  f16v acc[4][2];
#pragma unroll
  for (int mf = 0; mf < 4; ++mf)
#pragma unroll
    for (int nf = 0; nf < 2; ++nf) acc[mf][nf] = (f16v)0.0f;

  // prologue: stage K-tile 0 into buf 0 (A-kh0, B-kh0, A-kh1, B-kh1)
  STAGE(0, 0, 0);
  STAGE(1, 0, 0);
  STAGE(0, 1, 0);
  STAGE(1, 1, 0);
  VMW(4);          // kh0 A+B landed; kh1 pairs may fly
  SBAR();
  gA += 64; gA2 += 64; gB += 64; gB2 += 64;   // now point at K-tile 1

  s8v aP[4], aQ[4], bP[2], bQ[2];
  int curU = 0;
  RD32(aP, bP, 0, curU);

  for (int t = 0; t < NT; ++t) {
    const int nxtU = curU ^ 16384;
    // ---- P0: q0 MFMA; read q1 ----
    RD32(aQ, bQ, 1, curU);
    STAGE(0, 0, nxtU);
    SBAR(); mm8(acc, aP, bP);
    VMW(2);        // kh1(cur) A+B landed; publish via next barrier
    SBAR();
    // ---- P1: q1 MFMA; read q2 ----
    RD32(aP, bP, 2, curU);
    STAGE(1, 0, nxtU);
    SBAR(); mm8(acc, aQ, bQ); SBAR();
    // ---- P2: q2 MFMA; read q3 ----
    RD32(aQ, bQ, 3, curU);
    STAGE(0, 1, nxtU);
    SBAR(); mm8(acc, aP, bP);
    VMW(2);        // kh0(nxt) A+B landed; publish via next barrier
    SBAR();
    // ---- P3: q3 MFMA; read next tile's q0 from nxt ----
    RD32(aP, bP, 0, nxtU);
    STAGE(1, 1, nxtU);
    SBAR(); mm8(acc, aQ, bQ); SBAR();
    // advance pointers; wrap before the last tile's dummy prefetch (stays in-bounds)
    const long d = (t == NT - 2) ? -(long)((NT - 1) * 64) : 64;
    gA += d; gA2 += d; gB += d; gB2 += d;
    curU = nxtU;
  }
  VMW(0);          // drain dummy prefetch before retire

  // ---- epilogue: col = lane&31, row = (r&3) + 8*(r>>2) + 4*g ----
  const size_t crow = bm + wm * 128;
  const size_t ccol = bn + wn * 64 + l31;
  const int rbase = 4 * g;
#pragma unroll
  for (int mf = 0; mf < 4; ++mf)
#pragma unroll
    for (int nf = 0; nf < 2; ++nf) {
      float* cp = C + (crow + mf * 32) * (size_t)N + ccol + nf * 32;
#pragma unroll
      for (int r = 0; r < 16; ++r) {
        const int row = (r & 3) + 8 * (r >> 2) + rbase;
        cp[(size_t)row * N] = acc[mf][nf][r];
      }
    }
#undef STAGE
#undef RD32
}

// ---------- launch ----------
extern "C" void kernel_launch(void* const* d_in, const int* in_sizes, int n_in,
                              void* d_out, int out_size, void* d_ws, size_t ws_size,
                              hipStream_t stream) {
  const float* x  = (const float*)d_in[0];   // [8192,4096]
  const float* c0 = (const float*)d_in[1];   // [1,16,16,64]
  const float* c1 = (const float*)d_in[2];   // [64,16,16,64]
  const float* c2 = (const float*)d_in[3];   // [64,16,16,1]
  float* out = (float*)d_out;                // [8192,4096] fp32

  char* ws = (char*)d_ws;
  float*          T  = (float*)ws;                              // 16 MB
  unsigned short* Wb = (unsigned short*)(ws + (16u << 20));     // 32 MB  [out=4096][in=4096] bf16
  unsigned short* xb = (unsigned short*)(ws + (48u << 20));     // 64 MB  [8192][4096] bf16

  hipLaunchKernelGGL(cast_bf16, dim3(16384), dim3(256), 0, stream, x, xb);
  hipLaunchKernelGGL(contract1, dim3(16384), dim3(256), 0, stream, c0, c1, T);
  hipLaunchKernelGGL(buildW2,   dim3(256),   dim3(1024), 0, stream, T, c2, Wb);
  hipLaunchKernelGGL(gemm32,    dim3(512),   dim3(512), 0, stream, xb, Wb, out);
}

// Round 8
// 379.883 us; speedup vs baseline: 1.0645x; 1.0645x over previous
//
#include <hip/hip_runtime.h>

// ---------- types ----------
typedef __attribute__((ext_vector_type(8))) short  s8v;    // 8 bf16 (as shorts) = 4 VGPR
typedef __attribute__((ext_vector_type(8))) unsigned short us8;
typedef __attribute__((ext_vector_type(4))) float  f4v;    // MFMA accumulator

// float -> bf16 round-to-nearest-even (inputs are finite)
__device__ __forceinline__ unsigned short f2bf(float f) {
  unsigned int u = __builtin_bit_cast(unsigned int, f);
  u += 0x7fffu + ((u >> 16) & 1u);
  return (unsigned short)(u >> 16);
}

// async global->LDS, 16B per lane; offset arg must stay 0 (only verified mode).
__device__ __forceinline__ void gll16(const void* g, void* l) {
  __builtin_amdgcn_global_load_lds(
      (const __attribute__((address_space(1))) unsigned int*)g,
      (__attribute__((address_space(3))) unsigned int*)l, 16, 0, 0);
}

// ---------- kernel 1: x fp32 -> bf16 ----------
__global__ __launch_bounds__(256) void cast_bf16(const float* __restrict__ in,
                                                 unsigned short* __restrict__ out) {
  const size_t i = (size_t)blockIdx.x * 256 + threadIdx.x;
  const f4v* p = (const f4v*)in;
  f4v a = p[2 * i];
  f4v b = p[2 * i + 1];
  us8 r;
  r[0] = f2bf(a[0]); r[1] = f2bf(a[1]); r[2] = f2bf(a[2]); r[3] = f2bf(a[3]);
  r[4] = f2bf(b[0]); r[5] = f2bf(b[1]); r[6] = f2bf(b[2]); r[7] = f2bf(b[3]);
  *(us8*)&out[i * 8] = r;
}

// ---------- kernel 2: T[o1,i1,o2,i2,r2] = sum_r1 core0*core1 ----------
__global__ __launch_bounds__(256) void contract1(const float* __restrict__ c0,
                                                 const float* __restrict__ c1,
                                                 float* __restrict__ T) {
  const int idx = blockIdx.x * 256 + threadIdx.x;
  const int r2  = idx & 63;
  const int oi2 = (idx >> 6) & 255;
  const int oi1 = idx >> 14;
  const float* c0p = c0 + oi1 * 64;
  const float* c1p = c1 + oi2 * 64 + r2;
  float s = 0.f;
#pragma unroll 8
  for (int r1 = 0; r1 < 64; ++r1)
    s = fmaf(c0p[r1], c1p[r1 * 16384], s);
  T[idx] = s;
}

// ---------- kernel 3: W build, LDS-staged ----------
__global__ __launch_bounds__(1024) void buildW2(const float* __restrict__ T,
                                                const float* __restrict__ c2,
                                                unsigned short* __restrict__ W) {
  __shared__ float c2s[16384];      // 64 KB: [r2][o3][i3]
  __shared__ float Tl[16640];       // 65 KB: [ii][r2], stride 65

  const int tid = threadIdx.x;
  const int o1  = blockIdx.x >> 4;
  const int o2  = blockIdx.x & 15;

#pragma unroll
  for (int j = 0; j < 4; ++j)
    ((f4v*)c2s)[j * 1024 + tid] = ((const f4v*)c2)[j * 1024 + tid];

#pragma unroll
  for (int rr = 0; rr < 4; ++rr) {
    const int i1 = rr * 4 + (tid >> 8);
    const float* src = T + (size_t)(o1 * 16 + i1) * 16384 + o2 * 1024;
    const int c = tid & 255;
    f4v v = ((const f4v*)src)[c];
    float* dst = &Tl[(i1 * 16 + (c >> 4)) * 65 + (c & 15) * 4];
    dst[0] = v[0]; dst[1] = v[1]; dst[2] = v[2]; dst[3] = v[3];
  }
  __syncthreads();

  const int ii = tid & 255;
  const int i1 = ii >> 4, i2 = ii & 15;
#pragma unroll
  for (int k = 0; k < 4; ++k) {
    const int o3 = k * 4 + (tid >> 8);
    float acc[16];
#pragma unroll
    for (int j = 0; j < 16; ++j) acc[j] = 0.f;
    for (int r2 = 0; r2 < 64; ++r2) {
      const float t = Tl[ii * 65 + r2];
      const f4v* cp = (const f4v*)&c2s[r2 * 256 + o3 * 16];
      f4v c0q = cp[0], c1q = cp[1], c2q = cp[2], c3q = cp[3];
#pragma unroll
      for (int j = 0; j < 4; ++j) acc[j]      = fmaf(t, c0q[j], acc[j]);
#pragma unroll
      for (int j = 0; j < 4; ++j) acc[4 + j]  = fmaf(t, c1q[j], acc[4 + j]);
#pragma unroll
      for (int j = 0; j < 4; ++j) acc[8 + j]  = fmaf(t, c2q[j], acc[8 + j]);
#pragma unroll
      for (int j = 0; j < 4; ++j) acc[12 + j] = fmaf(t, c3q[j], acc[12 + j]);
    }
    us8 w0, w1;
#pragma unroll
    for (int j = 0; j < 8; ++j) { w0[j] = f2bf(acc[j]); w1[j] = f2bf(acc[8 + j]); }
    unsigned short* dst =
        &W[(size_t)(o1 * 256 + o2 * 16 + o3) * 4096 + i1 * 256 + i2 * 16];
    *(us8*)dst = w0;
    *((us8*)(dst + 8)) = w1;
  }
}

// ---------- kernel 4: 256x256-tile 8-phase GEMM, C = A * B^T ----------
// A[M][K], B[N][K] bf16, C[M][N] fp32. M=8192, N=4096, K=4096.
// LDS (ushort idx): A: buf*16384 + kh*8192 + row*32 + slot*8 ; B: +32768.
// Swizzle: 16B-slot ^= (row>>1)&3 on read; inverse on global source (rule #21).
// RAW BARRIERS (no memory-clobber asm): prefetch ds_reads may stay in flight
// across the barrier; compiler emits counted lgkmcnt before the consuming MFMA
// (m97 behavior). This is what lets the 576cy/phase LDS drain overlap the
// 620cy/phase MFMA window instead of serializing (R1..R6 all measured serial).

#define BAR() __builtin_amdgcn_s_barrier()
#define VMW(N) asm volatile("s_waitcnt vmcnt(" #N ")" ::: "memory")

template<int MH>
__device__ __forceinline__ void mm16(f4v (&acc)[8][4], const s8v (&aF)[4], const s8v (&bF)[4]) {
  __builtin_amdgcn_s_setprio(1);
#pragma unroll
  for (int m = 0; m < 4; ++m)
#pragma unroll
    for (int n = 0; n < 4; ++n)
      acc[MH * 4 + m][n] =
          __builtin_amdgcn_mfma_f32_16x16x32_bf16(aF[m], bF[n], acc[MH * 4 + m][n], 0, 0, 0);
  __builtin_amdgcn_s_setprio(0);
}

__global__ __launch_bounds__(512, 2) void gemm8(const unsigned short* __restrict__ A,
                                                const unsigned short* __restrict__ B,
                                                float* __restrict__ C) {
  constexpr int M = 8192, N = 4096, K = 4096;
  constexpr int NT = K / 64;      // 64 K-tiles
  constexpr int NXT = N / 256;    // 16 tiles in N

  __shared__ unsigned short lds[65536];   // 128 KiB

  const int tid  = threadIdx.x;
  const int lane = tid & 63;
  const int wid  = tid >> 6;      // 0..7
  const int wm   = wid >> 2;      // 0..1
  const int wn   = wid & 3;       // 0..3

  // XCD-aware bijective swizzle (gridDim.x = 512, divisible by 8)
  const int cpx = (int)gridDim.x >> 3;
  const int wg  = ((int)blockIdx.x & 7) * cpx + ((int)blockIdx.x >> 3);
  const long bm = (long)(wg / NXT) * 256;
  const long bn = (long)(wg % NXT) * 256;

  // ---- staging addressing (incremented pointers = VALU diet, proven R6) ----
  const int r0  = tid >> 2;
  const int sx0 = (tid & 3) ^ ((r0 >> 1) & 3);    // inverse-swizzled global 16B slot
  const unsigned short* gA  = A + (bm + r0) * (size_t)K + sx0 * 8;
  const unsigned short* gA2 = gA + 128 * (size_t)K;
  const unsigned short* gB  = B + (bn + r0) * (size_t)K + sx0 * 8;
  const unsigned short* gB2 = gB + 128 * (size_t)K;
  const int ldst = tid * 8;                        // linear LDS dest (ushorts)

#define STAGE(isB, KH, dstU) do {                                                \
    const unsigned short* gl_ = (isB ? gB : gA) + (KH) * 32;                     \
    const unsigned short* gh_ = (isB ? gB2 : gA2) + (KH) * 32;                   \
    unsigned short* l_ = &lds[(isB ? 32768 : 0) + (dstU) + (KH) * 8192 + ldst];  \
    gll16(gl_, l_);                                                              \
    gll16(gh_, l_ + 4096);                                                       \
  } while (0)

  // ---- fragment read addressing ----
  const int fr = lane & 15;
  const int ks = lane >> 4;                       // 0..3 (16B k-slot)
  const int swz = (ks ^ ((fr >> 1) & 3)) << 3;    // swizzled slot, ushort units
  const int aoff = (wm * 128 + fr) * 32 + swz;
  const int boff = (wn * 64 + fr) * 32 + swz;

#define RDA(dst, kh, bufU, mh) do {                                              \
    const unsigned short* p_ = &lds[(bufU) + (kh) * 8192 + aoff + (mh) * 2048];  \
    dst[0] = *(const s8v*)(p_);        dst[1] = *(const s8v*)(p_ + 512);         \
    dst[2] = *(const s8v*)(p_ + 1024); dst[3] = *(const s8v*)(p_ + 1536);        \
  } while (0)
#define RDB(dst, kh, bufU) do {                                                  \
    const unsigned short* p_ = &lds[32768 + (bufU) + (kh) * 8192 + boff];        \
    dst[0] = *(const s8v*)(p_);        dst[1] = *(const s8v*)(p_ + 512);         \
    dst[2] = *(const s8v*)(p_ + 1024); dst[3] = *(const s8v*)(p_ + 1536);        \
  } while (0)

  f4v acc[8][4];
#pragma unroll
  for (int m = 0; m < 8; ++m)
#pragma unroll
    for (int n = 0; n < 4; ++n) acc[m][n] = (f4v)0.0f;

  // prologue: stage K-tile 0 into buf 0 (A-kh0, B-kh0, A-kh1, B-kh1)
  STAGE(0, 0, 0);
  STAGE(1, 0, 0);
  STAGE(0, 1, 0);
  STAGE(1, 1, 0);
  VMW(4);          // kh0 A+B landed; kh1 pairs may fly
  BAR();
  gA += 64; gA2 += 64; gB += 64; gB2 += 64;   // now point at K-tile 1

  s8v aP[4], aQ[4], bP[4], bQ[4];
  int curU = 0;
  RDA(aP, 0, 0, 0);            // F0: A(mh0,kh0)
  RDB(bP, 0, 0);               //     B(kh0)

  for (int t = 0; t < NT; ++t) {
    const int nxtU = curU ^ 16384;
    // ---- P0: MFMA F0(aP,bP); read F1 ----
    RDA(aQ, 0, curU, 1);
    STAGE(0, 0, nxtU);
    BAR(); mm16<0>(acc, aP, bP);
    VMW(2);        // kh1(cur) A+B landed (staged 4-5 phases ago); publish via next barrier
    BAR();
    // ---- P1: MFMA F1(aQ,bP); read F2 ----
    RDA(aP, 1, curU, 0); RDB(bQ, 1, curU);
    STAGE(1, 0, nxtU);
    BAR(); mm16<1>(acc, aQ, bP); BAR();
    // ---- P2: MFMA F2(aP,bQ); read F3 ----
    RDA(aQ, 1, curU, 1);
    STAGE(0, 1, nxtU);
    BAR(); mm16<0>(acc, aP, bQ);
    VMW(2);        // kh0(nxt) A+B landed (staged 2-3 phases ago); publish via next barrier
    BAR();
    // ---- P3: MFMA F3(aQ,bQ); read F0 of next tile ----
    RDA(aP, 0, nxtU, 0); RDB(bP, 0, nxtU);
    STAGE(1, 1, nxtU);
    BAR(); mm16<1>(acc, aQ, bQ); BAR();
    // advance pointers; wrap before the last tile's dummy prefetch (stays in-bounds)
    const long d = (t == NT - 2) ? -(long)((NT - 1) * 64) : 64;
    gA += d; gA2 += d; gB += d; gB2 += d;
    curU = nxtU;
  }
  VMW(0);          // drain dummy prefetch before retire

  // ---- epilogue: C/D layout col = lane&15, row = (lane>>4)*4 + r ----
  const long crow0 = bm + wm * 128 + ks * 4;
  const long ccol0 = bn + wn * 64 + fr;
#pragma unroll
  for (int mf = 0; mf < 8; ++mf)
#pragma unroll
    for (int n = 0; n < 4; ++n)
#pragma unroll
      for (int r = 0; r < 4; ++r)
        C[(size_t)(crow0 + mf * 16 + r) * N + ccol0 + n * 16] = acc[mf][n][r];
#undef STAGE
#undef RDA
#undef RDB
}

// ---------- launch ----------
extern "C" void kernel_launch(void* const* d_in, const int* in_sizes, int n_in,
                              void* d_out, int out_size, void* d_ws, size_t ws_size,
                              hipStream_t stream) {
  const float* x  = (const float*)d_in[0];   // [8192,4096]
  const float* c0 = (const float*)d_in[1];   // [1,16,16,64]
  const float* c1 = (const float*)d_in[2];   // [64,16,16,64]
  const float* c2 = (const float*)d_in[3];   // [64,16,16,1]
  float* out = (float*)d_out;                // [8192,4096] fp32

  char* ws = (char*)d_ws;
  float*          T  = (float*)ws;                              // 16 MB
  unsigned short* Wb = (unsigned short*)(ws + (16u << 20));     // 32 MB  [out=4096][in=4096] bf16
  unsigned short* xb = (unsigned short*)(ws + (48u << 20));     // 64 MB  [8192][4096] bf16

  hipLaunchKernelGGL(cast_bf16, dim3(16384), dim3(256), 0, stream, x, xb);
  hipLaunchKernelGGL(contract1, dim3(16384), dim3(256), 0, stream, c0, c1, T);
  hipLaunchKernelGGL(buildW2,   dim3(256),   dim3(1024), 0, stream, T, c2, Wb);
  hipLaunchKernelGGL(gemm8,     dim3(512),   dim3(512), 0, stream, xb, Wb, out);
}